// Round 8
// baseline (148.610 us; speedup 1.0000x reference)
//
#include <hip/hip_runtime.h>

#define DEV __device__ __forceinline__

// Fixed-size value-semantics vector (pure SSA after inlining).
template <int N> struct V { float v[N == 0 ? 1 : N]; };

// General Batcher odd-even merge, by value (verified absmax=0.0 on HW, r2/3/5).
template <int M, int N>
DEV V<M + N> mrg(V<M> a, V<N> b) {
    V<M + N> o;
    if constexpr (M == 0) {
#pragma unroll
        for (int i = 0; i < N; ++i) o.v[i] = b.v[i];
    } else if constexpr (N == 0) {
#pragma unroll
        for (int i = 0; i < M; ++i) o.v[i] = a.v[i];
    } else if constexpr (M == 1 && N == 1) {
        o.v[0] = fminf(a.v[0], b.v[0]);
        o.v[1] = fmaxf(a.v[0], b.v[0]);
    } else if constexpr ((M & 1) && (N & 1)) {
        constexpr int AE = (M + 1) / 2, AO = M / 2, BE = (N + 1) / 2, BO = N / 2;
        V<AE> ae; V<AO> ao; V<BE> be; V<BO> bo;
#pragma unroll
        for (int i = 0; i < AE; ++i) ae.v[i] = a.v[2 * i];
#pragma unroll
        for (int i = 0; i < AO; ++i) ao.v[i] = a.v[2 * i + 1];
#pragma unroll
        for (int i = 0; i < BE; ++i) be.v[i] = b.v[2 * i];
#pragma unroll
        for (int i = 0; i < BO; ++i) bo.v[i] = b.v[2 * i + 1];
        V<AE + BO> E = mrg<AE, BO>(ae, bo);
        V<AO + BE> O = mrg<AO, BE>(ao, be);
        constexpr int P = AE + BO;
#pragma unroll
        for (int i = 0; i < P; ++i) {
            o.v[2 * i] = fminf(E.v[i], O.v[i]);
            o.v[2 * i + 1] = fmaxf(E.v[i], O.v[i]);
        }
    } else {
        constexpr int AE = (M + 1) / 2, AO = M / 2, BE = (N + 1) / 2, BO = N / 2;
        V<AE> ae; V<AO> ao; V<BE> be; V<BO> bo;
#pragma unroll
        for (int i = 0; i < AE; ++i) ae.v[i] = a.v[2 * i];
#pragma unroll
        for (int i = 0; i < AO; ++i) ao.v[i] = a.v[2 * i + 1];
#pragma unroll
        for (int i = 0; i < BE; ++i) be.v[i] = b.v[2 * i];
#pragma unroll
        for (int i = 0; i < BO; ++i) bo.v[i] = b.v[2 * i + 1];
        V<AE + BE> E = mrg<AE, BE>(ae, be);
        V<AO + BO> O = mrg<AO, BO>(ao, bo);
        constexpr int CEn = AE + BE, COn = AO + BO;
        o.v[0] = E.v[0];
#pragma unroll
        for (int i = 0; i < COn; ++i) {
            if (i + 1 < CEn) {
                o.v[2 * i + 1] = fminf(O.v[i], E.v[i + 1]);
                o.v[2 * i + 2] = fmaxf(O.v[i], E.v[i + 1]);
            } else {
                o.v[2 * i + 1] = O.v[i];
            }
        }
    }
    return o;
}

DEV void ce(float& a, float& b) {
    float lo = fminf(a, b);
    b = fmaxf(a, b);
    a = lo;
}

// sort7 = sort3 (min3/med3/max3) + sort4 (5 CE) + merge(3,4). (verified r5)
DEV V<7> sort7(V<7> x) {
    float a = x.v[0], b = x.v[1], c = x.v[2];
    V<3> s3;
    s3.v[0] = fminf(fminf(a, b), c);
    s3.v[1] = __builtin_amdgcn_fmed3f(a, b, c);
    s3.v[2] = fmaxf(fmaxf(a, b), c);
    ce(x.v[3], x.v[4]); ce(x.v[5], x.v[6]);
    ce(x.v[3], x.v[5]); ce(x.v[4], x.v[6]); ce(x.v[4], x.v[5]);
    V<4> s4;
    s4.v[0] = x.v[3]; s4.v[1] = x.v[4]; s4.v[2] = x.v[5]; s4.v[3] = x.v[6];
    return mrg<3, 4>(s3, s4);
}

// rank-24 of union(Q[28], F[21]), tree-reduced. (verified r5)
DEV float sel24(const V<28>& Q, const V<21>& F) {
    float t[22];
    t[21] = Q.v[24];
#pragma unroll
    for (int i = 4; i < 25; ++i) t[i - 4] = fmaxf(Q.v[i - 1], F.v[24 - i]);
#pragma unroll
    for (int i = 0; i < 11; ++i) t[i] = fminf(t[i], t[i + 11]);
#pragma unroll
    for (int i = 0; i < 5; ++i) t[i] = fminf(t[i], t[i + 6]);
#pragma unroll
    for (int i = 0; i < 3; ++i) t[i] = fminf(t[i], t[i + 3]);
    return fminf(fminf(t[0], t[1]), t[2]);
}

static constexpr int W = 512, H = 512, PLANE = W * H;

// Round-3 structure (2 rows/block, all loads upfront, no sched barriers)
// + med3 sort7 + tree sel24 + XCD swizzle
// + amdgpu_waves_per_eu(1,2): clamp scheduler's occupancy target to 2
//   waves/SIMD -> register-pressure limit 256 VGPRs -> stop AGPR shuttling.
__global__ __launch_bounds__(256) __attribute__((amdgpu_waves_per_eu(1, 2)))
void median7_hardtanh_kernel(const float* __restrict__ in,
                             float* __restrict__ out) {
    // XCD-aware bijective swizzle: 6144 blocks = 8 XCDs x 768 contiguous.
    int bid = (int)blockIdx.x;
    int swz = (bid & 7) * 768 + (bid >> 3);

    int local = (int)threadIdx.x;
    int tx = local & 127;          // 128 threads per row
    int ry = local >> 7;           // 2 rows per block
    int r = swz * 2 + ry;          // global row = plane*512 + y
    int y = r & (H - 1);
    int p = r >> 9;
    const float* img = in + (size_t)p * PLANE;
    int x0 = tx * 4;

    int rows[7];
#pragma unroll
    for (int i = 0; i < 7; ++i) {
        int t = y + i - 3;
        t = (t < 0) ? -t : t;
        t = (t > H - 1) ? 2 * (H - 1) - t : t;
        rows[i] = t << 9;
    }

    V<7> c0, c1, c2, c3, c4, c5, c6, c7, c8, c9;
    if (x0 >= 4 && x0 <= W - 8) {
        // interior: 3 aligned float4 loads per row cover cols x0-4 .. x0+7
#pragma unroll
        for (int i = 0; i < 7; ++i) {
            const float* rp = img + rows[i] + x0;
            float4 L = *reinterpret_cast<const float4*>(rp - 4);
            float4 C = *reinterpret_cast<const float4*>(rp);
            float4 R = *reinterpret_cast<const float4*>(rp + 4);
            c0.v[i] = L.y; c1.v[i] = L.z; c2.v[i] = L.w;
            c3.v[i] = C.x; c4.v[i] = C.y; c5.v[i] = C.z; c6.v[i] = C.w;
            c7.v[i] = R.x; c8.v[i] = R.y; c9.v[i] = R.z;
        }
    } else {
        // border threads (tx==0 or tx==127): branch-free reflected columns
        int cols[10];
#pragma unroll
        for (int j = 0; j < 10; ++j) {
            int u = x0 + j - 3;
            u = (u < 0) ? -u : u;
            u = (u > W - 1) ? 2 * (W - 1) - u : u;
            cols[j] = u;
        }
#pragma unroll
        for (int i = 0; i < 7; ++i) {
            const float* rp = img + rows[i];
            c0.v[i] = rp[cols[0]]; c1.v[i] = rp[cols[1]]; c2.v[i] = rp[cols[2]];
            c3.v[i] = rp[cols[3]]; c4.v[i] = rp[cols[4]]; c5.v[i] = rp[cols[5]];
            c6.v[i] = rp[cols[6]]; c7.v[i] = rp[cols[7]]; c8.v[i] = rp[cols[8]];
            c9.v[i] = rp[cols[9]];
        }
    }

    c0 = sort7(c0); c1 = sort7(c1); c2 = sort7(c2); c3 = sort7(c3);
    c4 = sort7(c4); c5 = sort7(c5); c6 = sort7(c6); c7 = sort7(c7);
    c8 = sort7(c8); c9 = sort7(c9);

    V<28> Q = mrg<14, 14>(mrg<7, 7>(c3, c4), mrg<7, 7>(c5, c6));
    V<14> P12 = mrg<7, 7>(c1, c2);
    V<14> P78 = mrg<7, 7>(c7, c8);

    float m0 = sel24(Q, mrg<14, 7>(P12, c0));
    float m1 = sel24(Q, mrg<14, 7>(P12, c7));
    float m2 = sel24(Q, mrg<14, 7>(P78, c2));
    float m3 = sel24(Q, mrg<14, 7>(P78, c9));

    float4 o;
    o.x = fminf(fmaxf(m0, 0.0f), 1.0f);
    o.y = fminf(fmaxf(m1, 0.0f), 1.0f);
    o.z = fminf(fmaxf(m2, 0.0f), 1.0f);
    o.w = fminf(fmaxf(m3, 0.0f), 1.0f);
    *reinterpret_cast<float4*>(out + (size_t)r * W + x0) = o;
}

extern "C" void kernel_launch(void* const* d_in, const int* in_sizes, int n_in,
                              void* d_out, int out_size, void* d_ws, size_t ws_size,
                              hipStream_t stream) {
    const float* x = (const float*)d_in[0];
    float* outp = (float*)d_out;
    int rows_total = out_size / W;      // 12288
    int blocks = rows_total / 2;        // 6144
    median7_hardtanh_kernel<<<blocks, 256, 0, stream>>>(x, outp);
}

// Round 9
// 130.361 us; speedup vs baseline: 1.1400x; 1.1400x over previous
//
#include <hip/hip_runtime.h>

#define DEV __device__ __forceinline__

// Fixed-size value-semantics vector (pure SSA after inlining).
template <int N> struct V { float v[N == 0 ? 1 : N]; };

// General Batcher odd-even merge, by value (verified absmax=0.0 on HW, r2/3/5/8).
template <int M, int N>
DEV V<M + N> mrg(V<M> a, V<N> b) {
    V<M + N> o;
    if constexpr (M == 0) {
#pragma unroll
        for (int i = 0; i < N; ++i) o.v[i] = b.v[i];
    } else if constexpr (N == 0) {
#pragma unroll
        for (int i = 0; i < M; ++i) o.v[i] = a.v[i];
    } else if constexpr (M == 1 && N == 1) {
        o.v[0] = fminf(a.v[0], b.v[0]);
        o.v[1] = fmaxf(a.v[0], b.v[0]);
    } else if constexpr ((M & 1) && (N & 1)) {
        constexpr int AE = (M + 1) / 2, AO = M / 2, BE = (N + 1) / 2, BO = N / 2;
        V<AE> ae; V<AO> ao; V<BE> be; V<BO> bo;
#pragma unroll
        for (int i = 0; i < AE; ++i) ae.v[i] = a.v[2 * i];
#pragma unroll
        for (int i = 0; i < AO; ++i) ao.v[i] = a.v[2 * i + 1];
#pragma unroll
        for (int i = 0; i < BE; ++i) be.v[i] = b.v[2 * i];
#pragma unroll
        for (int i = 0; i < BO; ++i) bo.v[i] = b.v[2 * i + 1];
        V<AE + BO> E = mrg<AE, BO>(ae, bo);
        V<AO + BE> O = mrg<AO, BE>(ao, be);
        constexpr int P = AE + BO;
#pragma unroll
        for (int i = 0; i < P; ++i) {
            o.v[2 * i] = fminf(E.v[i], O.v[i]);
            o.v[2 * i + 1] = fmaxf(E.v[i], O.v[i]);
        }
    } else {
        constexpr int AE = (M + 1) / 2, AO = M / 2, BE = (N + 1) / 2, BO = N / 2;
        V<AE> ae; V<AO> ao; V<BE> be; V<BO> bo;
#pragma unroll
        for (int i = 0; i < AE; ++i) ae.v[i] = a.v[2 * i];
#pragma unroll
        for (int i = 0; i < AO; ++i) ao.v[i] = a.v[2 * i + 1];
#pragma unroll
        for (int i = 0; i < BE; ++i) be.v[i] = b.v[2 * i];
#pragma unroll
        for (int i = 0; i < BO; ++i) bo.v[i] = b.v[2 * i + 1];
        V<AE + BE> E = mrg<AE, BE>(ae, be);
        V<AO + BO> O = mrg<AO, BO>(ao, bo);
        constexpr int CEn = AE + BE, COn = AO + BO;
        o.v[0] = E.v[0];
#pragma unroll
        for (int i = 0; i < COn; ++i) {
            if (i + 1 < CEn) {
                o.v[2 * i + 1] = fminf(O.v[i], E.v[i + 1]);
                o.v[2 * i + 2] = fmaxf(O.v[i], E.v[i + 1]);
            } else {
                o.v[2 * i + 1] = O.v[i];
            }
        }
    }
    return o;
}

DEV void ce(float& a, float& b) {
    float lo = fminf(a, b);
    b = fmaxf(a, b);
    a = lo;
}

// sort7 = sort3 (min3/med3/max3) + sort4 (5 CE) + merge(3,4). (verified r5/r8)
DEV V<7> sort7(V<7> x) {
    float a = x.v[0], b = x.v[1], c = x.v[2];
    V<3> s3;
    s3.v[0] = fminf(fminf(a, b), c);
    s3.v[1] = __builtin_amdgcn_fmed3f(a, b, c);
    s3.v[2] = fmaxf(fmaxf(a, b), c);
    ce(x.v[3], x.v[4]); ce(x.v[5], x.v[6]);
    ce(x.v[3], x.v[5]); ce(x.v[4], x.v[6]); ce(x.v[4], x.v[5]);
    V<4> s4;
    s4.v[0] = x.v[3]; s4.v[1] = x.v[4]; s4.v[2] = x.v[5]; s4.v[3] = x.v[6];
    return mrg<3, 4>(s3, s4);
}

// rank-24 (0-indexed) of union(A[0..41], c[0..6]) via the SAME two-list
// selection identity as the verified sel24: min over i+j==25 of
// max(A[i-1], c[j-1]); here j<=7 so i in [18,25] -> only 8 terms, and only
// A[17..24] is consumed (compiler DCE back-prunes the unused merge cone).
DEV float sel8(const V<42>& A, const V<7>& c) {
    float t0 = A.v[24];                    // i=25, j=0
    float t1 = fmaxf(A.v[23], c.v[0]);
    float t2 = fmaxf(A.v[22], c.v[1]);
    float t3 = fmaxf(A.v[21], c.v[2]);
    float t4 = fmaxf(A.v[20], c.v[3]);
    float t5 = fmaxf(A.v[19], c.v[4]);
    float t6 = fmaxf(A.v[18], c.v[5]);
    float t7 = fmaxf(A.v[17], c.v[6]);
    return fminf(fminf(fminf(t0, t1), fminf(t2, t3)),
                 fminf(fminf(t4, t5), fminf(t6, t7)));
}

static constexpr int W = 512, H = 512, PLANE = W * H;

// 2 rows/block, 4 px/thread, upfront loads, XCD swizzle (FETCH 12 MB, r8).
// waves_per_eu(1,3): occupancy cap 3 waves/SIMD (37.5%) with ~170-reg budget
// (r8 showed max=2's 17.5% starves latency hiding; r3 showed ~40% suffices).
// Decomposition per thread (pixels x0..x0+3, window cols c0..c9):
//   Q = merge(c3..c6)                     shared by all 4 px
//   QP12 = merge(Q, merge(c1,c2))         shared by px0,px1
//   QP78 = merge(Q, merge(c7,c8))         shared by px2,px3
//   px0 = sel8(QP12,c0)  px1 = sel8(QP12,c7)
//   px2 = sel8(QP78,c2)  px3 = sel8(QP78,c9)
__global__ __launch_bounds__(256) __attribute__((amdgpu_waves_per_eu(1, 3)))
void median7_hardtanh_kernel(const float* __restrict__ in,
                             float* __restrict__ out) {
    // XCD-aware bijective swizzle: 6144 blocks = 8 XCDs x 768 contiguous.
    int bid = (int)blockIdx.x;
    int swz = (bid & 7) * 768 + (bid >> 3);

    int local = (int)threadIdx.x;
    int tx = local & 127;          // 128 threads per row
    int ry = local >> 7;           // 2 rows per block
    int r = swz * 2 + ry;          // global row = plane*512 + y
    int y = r & (H - 1);
    int p = r >> 9;
    const float* img = in + (size_t)p * PLANE;
    int x0 = tx * 4;

    int rows[7];
#pragma unroll
    for (int i = 0; i < 7; ++i) {
        int t = y + i - 3;
        t = (t < 0) ? -t : t;
        t = (t > H - 1) ? 2 * (H - 1) - t : t;
        rows[i] = t << 9;
    }

    V<7> c0, c1, c2, c3, c4, c5, c6, c7, c8, c9;
    if (x0 >= 4 && x0 <= W - 8) {
        // interior: 3 aligned float4 loads per row cover cols x0-4 .. x0+7
#pragma unroll
        for (int i = 0; i < 7; ++i) {
            const float* rp = img + rows[i] + x0;
            float4 L = *reinterpret_cast<const float4*>(rp - 4);
            float4 C = *reinterpret_cast<const float4*>(rp);
            float4 R = *reinterpret_cast<const float4*>(rp + 4);
            c0.v[i] = L.y; c1.v[i] = L.z; c2.v[i] = L.w;
            c3.v[i] = C.x; c4.v[i] = C.y; c5.v[i] = C.z; c6.v[i] = C.w;
            c7.v[i] = R.x; c8.v[i] = R.y; c9.v[i] = R.z;
        }
    } else {
        // border threads (tx==0 or tx==127): branch-free reflected columns
        int cols[10];
#pragma unroll
        for (int j = 0; j < 10; ++j) {
            int u = x0 + j - 3;
            u = (u < 0) ? -u : u;
            u = (u > W - 1) ? 2 * (W - 1) - u : u;
            cols[j] = u;
        }
#pragma unroll
        for (int i = 0; i < 7; ++i) {
            const float* rp = img + rows[i];
            c0.v[i] = rp[cols[0]]; c1.v[i] = rp[cols[1]]; c2.v[i] = rp[cols[2]];
            c3.v[i] = rp[cols[3]]; c4.v[i] = rp[cols[4]]; c5.v[i] = rp[cols[5]];
            c6.v[i] = rp[cols[6]]; c7.v[i] = rp[cols[7]]; c8.v[i] = rp[cols[8]];
            c9.v[i] = rp[cols[9]];
        }
    }

    c0 = sort7(c0); c1 = sort7(c1); c2 = sort7(c2); c3 = sort7(c3);
    c4 = sort7(c4); c5 = sort7(c5); c6 = sort7(c6); c7 = sort7(c7);
    c8 = sort7(c8); c9 = sort7(c9);

    V<28> Q = mrg<14, 14>(mrg<7, 7>(c3, c4), mrg<7, 7>(c5, c6));

    V<42> QP12 = mrg<28, 14>(Q, mrg<7, 7>(c1, c2));
    float m0 = sel8(QP12, c0);
    float m1 = sel8(QP12, c7);

    V<42> QP78 = mrg<28, 14>(Q, mrg<7, 7>(c7, c8));
    float m2 = sel8(QP78, c2);
    float m3 = sel8(QP78, c9);

    float4 o;
    o.x = fminf(fmaxf(m0, 0.0f), 1.0f);
    o.y = fminf(fmaxf(m1, 0.0f), 1.0f);
    o.z = fminf(fmaxf(m2, 0.0f), 1.0f);
    o.w = fminf(fmaxf(m3, 0.0f), 1.0f);
    *reinterpret_cast<float4*>(out + (size_t)r * W + x0) = o;
}

extern "C" void kernel_launch(void* const* d_in, const int* in_sizes, int n_in,
                              void* d_out, int out_size, void* d_ws, size_t ws_size,
                              hipStream_t stream) {
    const float* x = (const float*)d_in[0];
    float* outp = (float*)d_out;
    int rows_total = out_size / W;      // 12288
    int blocks = rows_total / 2;        // 6144
    median7_hardtanh_kernel<<<blocks, 256, 0, stream>>>(x, outp);
}